// Round 3
// baseline (1754.948 us; speedup 1.0000x reference)
//
#include <hip/hip_runtime.h>
#include <stdint.h>

#define NB 2048
#define NT 128

typedef __attribute__((ext_vector_type(8))) short bf16x8;
typedef __attribute__((ext_vector_type(4))) float f32x4;

// pack two fp32 into one dword of 2 bf16 (truncation): low16 = hi16(a), high16 = hi16(b)
__device__ __forceinline__ uint32_t pk_hi(float a, float b) {
    return __builtin_amdgcn_perm(__float_as_uint(b), __float_as_uint(a), 0x07060302u);
}
__device__ __forceinline__ float bftrunc(float a) {
    return __uint_as_float(__float_as_uint(a) & 0xFFFF0000u);
}

union FragU { uint32_t u[4]; bf16x8 v; };

__device__ __forceinline__ bf16x8 frag_hi(const float* x) {
    FragU r;
    #pragma unroll
    for (int i = 0; i < 4; ++i) r.u[i] = pk_hi(x[2*i], x[2*i+1]);
    return r.v;
}
__device__ __forceinline__ bf16x8 frag_lo(const float* x) {
    FragU r;
    #pragma unroll
    for (int i = 0; i < 4; ++i) {
        float e = x[2*i]   - bftrunc(x[2*i]);
        float o = x[2*i+1] - bftrunc(x[2*i+1]);
        r.u[i] = pk_hi(e, o);
    }
    return r.v;
}

#define MFMA(a, b, c) __builtin_amdgcn_mfma_f32_16x16x32_bf16((a), (b), (c), 0, 0, 0)

// ---------------------------------------------------------------------------
// Kernel 1: action-latent MLP  (B*T, 8) -> relu(64) -> (B*T, 16), into d_ws
// ---------------------------------------------------------------------------
__global__ __launch_bounds__(256, 4) void acl_kernel(
    const float* __restrict__ acs, const float* __restrict__ acW0,
    const float* __restrict__ acb0, const float* __restrict__ acW1,
    const float* __restrict__ acb1, float* __restrict__ aclout)
{
    __shared__ float sW0[64 * 8];
    __shared__ float sW1[16 * 64];
    __shared__ float sB0[64];
    __shared__ float sB1[16];
    const int tid = threadIdx.x;
    for (int i = tid; i < 64 * 8; i += 256) sW0[i] = acW0[i];
    for (int i = tid; i < 16 * 64; i += 256) sW1[i] = acW1[i];
    if (tid < 64) sB0[tid] = acb0[tid];
    if (tid < 16) sB1[tid] = acb1[tid];
    __syncthreads();

    const int row = blockIdx.x * 256 + tid;
    const f32x4 x0 = *(const f32x4*)&acs[row * 8];
    const f32x4 x1 = *(const f32x4*)&acs[row * 8 + 4];

    float o[16];
    #pragma unroll
    for (int m = 0; m < 16; ++m) o[m] = sB1[m];

    #pragma unroll
    for (int jc = 0; jc < 16; ++jc) {
        float hq[4];
        #pragma unroll
        for (int u = 0; u < 4; ++u) {
            const int j = jc * 4 + u;
            const f32x4 wa = *(const f32x4*)&sW0[j * 8];
            const f32x4 wb = *(const f32x4*)&sW0[j * 8 + 4];
            float hv = sB0[j];
            hv = fmaf(x0[0], wa[0], hv); hv = fmaf(x0[1], wa[1], hv);
            hv = fmaf(x0[2], wa[2], hv); hv = fmaf(x0[3], wa[3], hv);
            hv = fmaf(x1[0], wb[0], hv); hv = fmaf(x1[1], wb[1], hv);
            hv = fmaf(x1[2], wb[2], hv); hv = fmaf(x1[3], wb[3], hv);
            hq[u] = fmaxf(hv, 0.f);
        }
        #pragma unroll
        for (int m = 0; m < 16; ++m) {
            const f32x4 wv = *(const f32x4*)&sW1[m * 64 + jc * 4];
            o[m] = fmaf(hq[0], wv[0], o[m]);
            o[m] = fmaf(hq[1], wv[1], o[m]);
            o[m] = fmaf(hq[2], wv[2], o[m]);
            o[m] = fmaf(hq[3], wv[3], o[m]);
        }
    }
    #pragma unroll
    for (int q = 0; q < 4; ++q) {
        f32x4 v; v[0]=o[4*q]; v[1]=o[4*q+1]; v[2]=o[4*q+2]; v[3]=o[4*q+3];
        *(f32x4*)&aclout[row * 16 + 4*q] = v;
    }
}

// ---------------------------------------------------------------------------
// Kernel 2: encoder  (B, 64) -> relu(64) -> (B, 32), per-thread row
// ---------------------------------------------------------------------------
__global__ __launch_bounds__(256, 2) void enc_kernel(
    const float* __restrict__ ob, const float* __restrict__ encW0,
    const float* __restrict__ encb0, const float* __restrict__ encW1,
    const float* __restrict__ encb1, float* __restrict__ y0ws)
{
    __shared__ float sW0[64 * 64];   // [j][k]
    __shared__ float sW1T[64 * 32];  // [j][n]
    __shared__ float sB0[64], sB1[32];
    const int tid = threadIdx.x;
    for (int i = tid; i < 64 * 64; i += 256) sW0[i] = encW0[i];
    for (int i = tid; i < 32 * 64; i += 256) { int n = i >> 6, j = i & 63; sW1T[j * 32 + n] = encW1[i]; }
    if (tid < 64) sB0[tid] = encb0[tid];
    if (tid < 32) sB1[tid] = encb1[tid];
    __syncthreads();

    const int row = blockIdx.x * 256 + tid;   // B rows
    f32x4 xv[16];
    #pragma unroll
    for (int q = 0; q < 16; ++q) xv[q] = *(const f32x4*)&ob[row * 64 + 4 * q];
    float o[32];
    #pragma unroll
    for (int n = 0; n < 32; ++n) o[n] = sB1[n];
    #pragma unroll 4
    for (int j = 0; j < 64; ++j) {
        float h = sB0[j];
        #pragma unroll
        for (int q = 0; q < 16; ++q) {
            const f32x4 wv = *(const f32x4*)&sW0[j * 64 + 4 * q];
            h = fmaf(xv[q][0], wv[0], h); h = fmaf(xv[q][1], wv[1], h);
            h = fmaf(xv[q][2], wv[2], h); h = fmaf(xv[q][3], wv[3], h);
        }
        h = fmaxf(h, 0.f);
        #pragma unroll
        for (int q = 0; q < 8; ++q) {
            const f32x4 wv = *(const f32x4*)&sW1T[j * 32 + 4 * q];
            o[4*q+0] = fmaf(h, wv[0], o[4*q+0]);
            o[4*q+1] = fmaf(h, wv[1], o[4*q+1]);
            o[4*q+2] = fmaf(h, wv[2], o[4*q+2]);
            o[4*q+3] = fmaf(h, wv[3], o[4*q+3]);
        }
    }
    #pragma unroll
    for (int q = 0; q < 8; ++q) {
        f32x4 v; v[0]=o[4*q]; v[1]=o[4*q+1]; v[2]=o[4*q+2]; v[3]=o[4*q+3];
        *(f32x4*)&y0ws[row * 32 + 4 * q] = v;
    }
}

// ---------------------------------------------------------------------------
// Kernel 3: ODE time loop, MFMA. One wave = 16 batch elements.
// Everything computed transposed (Hᵀ = W0·Xᵀ, Oᵀ = W1·Hᵀ) so state stays in
// the verified C/D layout: col = lane&15 = batch, row = 4*quad + reg = feature.
// Weights live as static A-fragments (A[m=lane&15][k=quad*8+j]) in VGPRs,
// hi/lo bf16 truncation-split for ~fp32 precision.
// acl contribution is linear + interval-constant -> precomputed C-partial.
// ---------------------------------------------------------------------------
__global__ __launch_bounds__(64, 1) void ode_kernel(
    const float* __restrict__ dynW0, const float* __restrict__ dynb0,
    const float* __restrict__ dynW1, const float* __restrict__ dynb1,
    const float* __restrict__ times, const float* __restrict__ aclws,
    const float* __restrict__ y0ws,  float* __restrict__ ysws)
{
    // staging grid: [batch-col 16][feature-rowpair 32] dwords (2 bf16 each)
    __shared__ uint32_t stgH[16 * 32];
    __shared__ uint32_t stgL[16 * 32];
    __shared__ float tb[NT];

    const int lane  = threadIdx.x;   // 64
    const int g     = lane >> 4;     // quad
    const int col   = lane & 15;
    const int bbase = blockIdx.x * 16;
    const int bcol  = bbase + col;

    tb[lane]      = times[(size_t)bbase * NT + lane];
    tb[64 + lane] = times[(size_t)bbase * NT + 64 + lane];

    // ---- static weight fragments
    bf16x8 w0yH[4], w0yL[4], w0aH[4], w0aL[4], w1H[2][2], w1L[2][2];
    #pragma unroll
    for (int t = 0; t < 4; ++t) {
        float v[8];
        *(f32x4*)&v[0] = *(const f32x4*)&dynW0[(16 * t + col) * 48 + 8 * g];
        *(f32x4*)&v[4] = *(const f32x4*)&dynW0[(16 * t + col) * 48 + 8 * g + 4];
        w0yH[t] = frag_hi(v); w0yL[t] = frag_lo(v);
        float a[8] = {0, 0, 0, 0, 0, 0, 0, 0};
        if (g < 2) {
            *(f32x4*)&a[0] = *(const f32x4*)&dynW0[(16 * t + col) * 48 + 32 + 8 * g];
            *(f32x4*)&a[4] = *(const f32x4*)&dynW0[(16 * t + col) * 48 + 32 + 8 * g + 4];
        }
        w0aH[t] = frag_hi(a); w0aL[t] = frag_lo(a);
    }
    #pragma unroll
    for (int t1 = 0; t1 < 2; ++t1) {
        #pragma unroll
        for (int kt = 0; kt < 2; ++kt) {
            float v[8];
            *(f32x4*)&v[0] = *(const f32x4*)&dynW1[(16 * t1 + col) * 64 + 32 * kt + 8 * g];
            *(f32x4*)&v[4] = *(const f32x4*)&dynW1[(16 * t1 + col) * 64 + 32 * kt + 8 * g + 4];
            w1H[t1][kt] = frag_hi(v); w1L[t1][kt] = frag_lo(v);
        }
    }

    // biases in C layout (broadcast over batch cols)
    f32x4 b0C[4], b1C[2];
    #pragma unroll
    for (int t = 0; t < 4; ++t) {
        #pragma unroll
        for (int r = 0; r < 4; ++r) b0C[t][r] = dynb0[16 * t + 4 * g + r];
    }
    #pragma unroll
    for (int t1 = 0; t1 < 2; ++t1) {
        #pragma unroll
        for (int r = 0; r < 4; ++r) b1C[t1][r] = dynb1[16 * t1 + 4 * g + r];
    }

    // ---- y0 in C layout
    f32x4 y[2];
    y[0] = *(const f32x4*)&y0ws[(size_t)bcol * 32 + 4 * g];
    y[1] = *(const f32x4*)&y0ws[(size_t)bcol * 32 + 16 + 4 * g];
    *(f32x4*)&ysws[((size_t)bcol * NT + 0) * 32 + 4 * g]      = y[0];
    *(f32x4*)&ysws[((size_t)bcol * NT + 0) * 32 + 16 + 4 * g] = y[1];

    auto load_acl = [&](float* av, int t) {
        #pragma unroll
        for (int q = 0; q < 8; ++q) av[q] = 0.f;
        if (g < 2) {
            *(f32x4*)&av[0] = *(const f32x4*)&aclws[((size_t)bcol * NT + t) * 16 + 8 * g];
            *(f32x4*)&av[4] = *(const f32x4*)&aclws[((size_t)bcol * NT + t) * 16 + 8 * g + 4];
        }
    };
    auto acl_c = [&](const float* av, f32x4* cdst) {
        const bf16x8 aH = frag_hi(av), aL = frag_lo(av);
        #pragma unroll
        for (int t = 0; t < 4; ++t)
            cdst[t] = MFMA(w0aL[t], aH, MFMA(w0aH[t], aL, MFMA(w0aH[t], aH, b0C[t])));
    };

    // f: xs (2 C-tiles, y-state) + cin (4 C-tiles, b0+acl partial) -> o (2 C-tiles)
    auto feval = [&](const f32x4* xs, const f32x4* cin, f32x4* o) {
        // stage y: rowpair grid writes (both bf16-hi and residual-lo)
        #pragma unroll
        for (int t = 0; t < 2; ++t) {
            uint2 hw, lw;
            hw.x = pk_hi(xs[t][0], xs[t][1]);
            hw.y = pk_hi(xs[t][2], xs[t][3]);
            float l0 = xs[t][0] - bftrunc(xs[t][0]);
            float l1 = xs[t][1] - bftrunc(xs[t][1]);
            float l2 = xs[t][2] - bftrunc(xs[t][2]);
            float l3 = xs[t][3] - bftrunc(xs[t][3]);
            lw.x = pk_hi(l0, l1);
            lw.y = pk_hi(l2, l3);
            const int rp = col * 32 + 8 * t + 2 * g;
            *(uint2*)&stgH[rp] = hw;
            *(uint2*)&stgL[rp] = lw;
        }
        __builtin_amdgcn_wave_barrier();
        const bf16x8 xh = *(const bf16x8*)&stgH[col * 32 + 4 * g];
        const bf16x8 xl = *(const bf16x8*)&stgL[col * 32 + 4 * g];
        // layer 0: Hᵀ = W0y·Yᵀ + (b0 + W0a·ACLᵀ)
        f32x4 c[4];
        #pragma unroll
        for (int t = 0; t < 4; ++t) {
            c[t] = MFMA(w0yL[t], xh, cin[t]);
            c[t] = MFMA(w0yH[t], xl, c[t]);
            c[t] = MFMA(w0yH[t], xh, c[t]);
        }
        __builtin_amdgcn_wave_barrier();
        // relu + stage H
        #pragma unroll
        for (int t = 0; t < 4; ++t) {
            float h0 = fmaxf(c[t][0], 0.f), h1 = fmaxf(c[t][1], 0.f);
            float h2 = fmaxf(c[t][2], 0.f), h3 = fmaxf(c[t][3], 0.f);
            uint2 hw, lw;
            hw.x = pk_hi(h0, h1); hw.y = pk_hi(h2, h3);
            float l0 = h0 - bftrunc(h0), l1 = h1 - bftrunc(h1);
            float l2 = h2 - bftrunc(h2), l3 = h3 - bftrunc(h3);
            lw.x = pk_hi(l0, l1); lw.y = pk_hi(l2, l3);
            const int rp = col * 32 + 8 * t + 2 * g;
            *(uint2*)&stgH[rp] = hw;
            *(uint2*)&stgL[rp] = lw;
        }
        __builtin_amdgcn_wave_barrier();
        const bf16x8 h0h = *(const bf16x8*)&stgH[col * 32 + 4 * g];
        const bf16x8 h0l = *(const bf16x8*)&stgL[col * 32 + 4 * g];
        const bf16x8 h1h = *(const bf16x8*)&stgH[col * 32 + 16 + 4 * g];
        const bf16x8 h1l = *(const bf16x8*)&stgL[col * 32 + 16 + 4 * g];
        __builtin_amdgcn_wave_barrier();
        // layer 1: Oᵀ = W1·Hᵀ + b1
        #pragma unroll
        for (int t1 = 0; t1 < 2; ++t1) {
            f32x4 oo = b1C[t1];
            oo = MFMA(w1L[t1][0], h0h, oo);
            oo = MFMA(w1H[t1][0], h0l, oo);
            oo = MFMA(w1H[t1][0], h0h, oo);
            oo = MFMA(w1L[t1][1], h1h, oo);
            oo = MFMA(w1H[t1][1], h1l, oo);
            oo = MFMA(w1H[t1][1], h1h, oo);
            o[t1] = oo;
        }
    };

    // prime acl pipeline
    float av[8];
    load_acl(av, 0);
    f32x4 caclC[4];
    acl_c(av, caclC);
    load_acl(av, 1);

    for (int i = 0; i < NT - 1; ++i) {
        const float t0v = tb[i];
        const float t1v = tb[i + 1];
        const float hh  = (t1v - t0v) * 0.5f;     // /K, K=2

        // C-partial for interval i+1 (av holds acl[i+1]); then prefetch acl[i+2]
        f32x4 caclN[4];
        acl_c(av, caclN);
        const int nxt = (i + 2 <= NT - 1) ? (i + 2) : (NT - 1);
        load_acl(av, nxt);

        #pragma unroll 1
        for (int sub = 0; sub < 2; ++sub) {
            const float tsub  = t0v + (float)sub * hh;
            // stage-6 time fl(tsub+hh): matches reference searchsorted('right')
            const bool  swap6 = (tsub + hh >= t1v);
            f32x4 c6[4];
            #pragma unroll
            for (int t = 0; t < 4; ++t) c6[t] = swap6 ? caclN[t] : caclC[t];

            f32x4 xs[2], k1[2], k2[2], k3[2], k4[2], k5[2], k6[2];
            feval(y, caclC, k1);
            #pragma unroll
            for (int t = 0; t < 2; ++t) xs[t] = y[t] + hh * (0.2f * k1[t]);
            feval(xs, caclC, k2);
            #pragma unroll
            for (int t = 0; t < 2; ++t) xs[t] = y[t] + hh * (0.075f * k1[t] + 0.225f * k2[t]);
            feval(xs, caclC, k3);
            #pragma unroll
            for (int t = 0; t < 2; ++t) xs[t] = y[t] + hh * ((float)(44.0/45.0) * k1[t]
                + (float)(-56.0/15.0) * k2[t] + (float)(32.0/9.0) * k3[t]);
            feval(xs, caclC, k4);
            #pragma unroll
            for (int t = 0; t < 2; ++t) xs[t] = y[t] + hh * ((float)(19372.0/6561.0) * k1[t]
                + (float)(-25360.0/2187.0) * k2[t] + (float)(64448.0/6561.0) * k3[t]
                + (float)(-212.0/729.0) * k4[t]);
            feval(xs, caclC, k5);
            #pragma unroll
            for (int t = 0; t < 2; ++t) xs[t] = y[t] + hh * ((float)(9017.0/3168.0) * k1[t]
                + (float)(-355.0/33.0) * k2[t] + (float)(46732.0/5247.0) * k3[t]
                + (float)(49.0/176.0) * k4[t] + (float)(-5103.0/18656.0) * k5[t]);
            feval(xs, c6, k6);
            #pragma unroll
            for (int t = 0; t < 2; ++t) y[t] = y[t] + hh * ((float)(35.0/384.0) * k1[t]
                + (float)(500.0/1113.0) * k3[t] + (float)(125.0/192.0) * k4[t]
                + (float)(-2187.0/6784.0) * k5[t] + (float)(11.0/84.0) * k6[t]);
        }
        #pragma unroll
        for (int t = 0; t < 4; ++t) caclC[t] = caclN[t];
        *(f32x4*)&ysws[((size_t)bcol * NT + (i + 1)) * 32 + 4 * g]      = y[0];
        *(f32x4*)&ysws[((size_t)bcol * NT + (i + 1)) * 32 + 16 + 4 * g] = y[1];
    }
}

// ---------------------------------------------------------------------------
// Kernel 4: decoder  (B*T, 32) -> relu(64) -> (B*T, 64), per-thread row
// ---------------------------------------------------------------------------
__global__ __launch_bounds__(256, 2) void dec_kernel(
    const float* __restrict__ ysws, const float* __restrict__ decW0,
    const float* __restrict__ decb0, const float* __restrict__ decW1,
    const float* __restrict__ decb1, float* __restrict__ out)
{
    __shared__ float sW0[64 * 32];   // [j][k]
    __shared__ float sW1T[64 * 64];  // [j][n]
    __shared__ float sB0[64], sB1[64];
    const int tid = threadIdx.x;
    for (int i = tid; i < 64 * 32; i += 256) sW0[i] = decW0[i];
    for (int i = tid; i < 64 * 64; i += 256) { int n = i >> 6, j = i & 63; sW1T[j * 64 + n] = decW1[i]; }
    if (tid < 64) { sB0[tid] = decb0[tid]; sB1[tid] = decb1[tid]; }
    __syncthreads();

    const size_t row = (size_t)blockIdx.x * 256 + tid;   // B*T rows
    f32x4 yv[8];
    #pragma unroll
    for (int q = 0; q < 8; ++q) yv[q] = *(const f32x4*)&ysws[row * 32 + 4 * q];
    float o[64];
    #pragma unroll
    for (int n = 0; n < 64; ++n) o[n] = sB1[n];
    #pragma unroll 2
    for (int j = 0; j < 64; ++j) {
        float h = sB0[j];
        #pragma unroll
        for (int q = 0; q < 8; ++q) {
            const f32x4 wv = *(const f32x4*)&sW0[j * 32 + 4 * q];
            h = fmaf(yv[q][0], wv[0], h); h = fmaf(yv[q][1], wv[1], h);
            h = fmaf(yv[q][2], wv[2], h); h = fmaf(yv[q][3], wv[3], h);
        }
        h = fmaxf(h, 0.f);
        #pragma unroll
        for (int q = 0; q < 16; ++q) {
            const f32x4 wv = *(const f32x4*)&sW1T[j * 64 + 4 * q];
            o[4*q+0] = fmaf(h, wv[0], o[4*q+0]);
            o[4*q+1] = fmaf(h, wv[1], o[4*q+1]);
            o[4*q+2] = fmaf(h, wv[2], o[4*q+2]);
            o[4*q+3] = fmaf(h, wv[3], o[4*q+3]);
        }
    }
    #pragma unroll
    for (int q = 0; q < 16; ++q) {
        f32x4 v; v[0]=o[4*q]; v[1]=o[4*q+1]; v[2]=o[4*q+2]; v[3]=o[4*q+3];
        *(f32x4*)&out[row * 64 + 4 * q] = v;
    }
}

extern "C" void kernel_launch(void* const* d_in, const int* in_sizes, int n_in,
                              void* d_out, int out_size, void* d_ws, size_t ws_size,
                              hipStream_t stream)
{
    const float* encW0 = (const float*)d_in[0];
    const float* encb0 = (const float*)d_in[1];
    const float* encW1 = (const float*)d_in[2];
    const float* encb1 = (const float*)d_in[3];
    const float* acW0  = (const float*)d_in[4];
    const float* acb0  = (const float*)d_in[5];
    const float* acW1  = (const float*)d_in[6];
    const float* acb1  = (const float*)d_in[7];
    const float* dynW0 = (const float*)d_in[8];
    const float* dynb0 = (const float*)d_in[9];
    const float* dynW1 = (const float*)d_in[10];
    const float* dynb1 = (const float*)d_in[11];
    const float* decW0 = (const float*)d_in[12];
    const float* decb0 = (const float*)d_in[13];
    const float* decW1 = (const float*)d_in[14];
    const float* decb1 = (const float*)d_in[15];
    const float* ob    = (const float*)d_in[16];
    const float* acs   = (const float*)d_in[17];
    const float* times = (const float*)d_in[18];
    float* out = (float*)d_out;

    float* acl  = (float*)d_ws;                       // NB*NT*16 f32 = 16.78 MB
    float* ency = acl  + (size_t)NB * NT * 16;        // NB*32       =  0.26 MB
    float* ys   = ency + (size_t)NB * 32;             // NB*NT*32    = 33.55 MB

    acl_kernel<<<(NB * NT) / 256, 256, 0, stream>>>(acs, acW0, acb0, acW1, acb1, acl);
    enc_kernel<<<NB / 256, 256, 0, stream>>>(ob, encW0, encb0, encW1, encb1, ency);
    ode_kernel<<<NB / 16, 64, 0, stream>>>(dynW0, dynb0, dynW1, dynb1,
                                           times, acl, ency, ys);
    dec_kernel<<<(NB * NT) / 256, 256, 0, stream>>>(ys, decW0, decb0, decW1, decb1, out);
}

// Round 5
// 1099.978 us; speedup vs baseline: 1.5954x; 1.5954x over previous
//
#include <hip/hip_runtime.h>
#include <stdint.h>

#define NB 2048
#define NT 128

typedef __attribute__((ext_vector_type(4))) float f32x4;
typedef __attribute__((ext_vector_type(2))) __fp16 fp16x2;
typedef __attribute__((ext_vector_type(4))) _Float16 f16x4;

#define MFMA16(a, b, c) __builtin_amdgcn_mfma_f32_16x16x16f16((a), (b), (c), 0, 0, 0)
#define INV2048 (1.0f / 2048.0f)

union F4u { fp16x2 h2[2]; f16x4 v; };

__device__ __forceinline__ f16x4 pack4(float a, float b, float c, float d) {
    F4u u;
    u.h2[0] = __builtin_amdgcn_cvt_pkrtz(a, b);
    u.h2[1] = __builtin_amdgcn_cvt_pkrtz(c, d);
    return u.v;
}
__device__ __forceinline__ f16x4 packC(const f32x4 x) { return pack4(x[0], x[1], x[2], x[3]); }

// 2-term weight split: hi = f16(w), lo = (w - hi) * 2048 (kept normal-range)
__device__ __forceinline__ void split4(const f32x4 w, f16x4& hi, f16x4& lo) {
    f16x4 h = packC(w);
    hi = h;
    lo = pack4((w[0] - (float)h[0]) * 2048.f, (w[1] - (float)h[1]) * 2048.f,
               (w[2] - (float)h[2]) * 2048.f, (w[3] - (float)h[3]) * 2048.f);
}
__device__ __forceinline__ f32x4 relu4(f32x4 x) {
    f32x4 r;
    r[0] = fmaxf(x[0], 0.f); r[1] = fmaxf(x[1], 0.f);
    r[2] = fmaxf(x[2], 0.f); r[3] = fmaxf(x[3], 0.f);
    return r;
}

// ---------------------------------------------------------------------------
// Kernel 1: action-latent MLP  (B*T, 8) -> relu(64) -> (B*T, 16), into d_ws
// ---------------------------------------------------------------------------
__global__ __launch_bounds__(256, 4) void acl_kernel(
    const float* __restrict__ acs, const float* __restrict__ acW0,
    const float* __restrict__ acb0, const float* __restrict__ acW1,
    const float* __restrict__ acb1, float* __restrict__ aclout)
{
    __shared__ float sW0[64 * 8];
    __shared__ float sW1[16 * 64];
    __shared__ float sB0[64];
    __shared__ float sB1[16];
    const int tid = threadIdx.x;
    for (int i = tid; i < 64 * 8; i += 256) sW0[i] = acW0[i];
    for (int i = tid; i < 16 * 64; i += 256) sW1[i] = acW1[i];
    if (tid < 64) sB0[tid] = acb0[tid];
    if (tid < 16) sB1[tid] = acb1[tid];
    __syncthreads();

    const int row = blockIdx.x * 256 + tid;
    const f32x4 x0 = *(const f32x4*)&acs[row * 8];
    const f32x4 x1 = *(const f32x4*)&acs[row * 8 + 4];

    float o[16];
    #pragma unroll
    for (int m = 0; m < 16; ++m) o[m] = sB1[m];

    #pragma unroll
    for (int jc = 0; jc < 16; ++jc) {
        float hq[4];
        #pragma unroll
        for (int u = 0; u < 4; ++u) {
            const int j = jc * 4 + u;
            const f32x4 wa = *(const f32x4*)&sW0[j * 8];
            const f32x4 wb = *(const f32x4*)&sW0[j * 8 + 4];
            float hv = sB0[j];
            hv = fmaf(x0[0], wa[0], hv); hv = fmaf(x0[1], wa[1], hv);
            hv = fmaf(x0[2], wa[2], hv); hv = fmaf(x0[3], wa[3], hv);
            hv = fmaf(x1[0], wb[0], hv); hv = fmaf(x1[1], wb[1], hv);
            hv = fmaf(x1[2], wb[2], hv); hv = fmaf(x1[3], wb[3], hv);
            hq[u] = fmaxf(hv, 0.f);
        }
        #pragma unroll
        for (int m = 0; m < 16; ++m) {
            const f32x4 wv = *(const f32x4*)&sW1[m * 64 + jc * 4];
            o[m] = fmaf(hq[0], wv[0], o[m]);
            o[m] = fmaf(hq[1], wv[1], o[m]);
            o[m] = fmaf(hq[2], wv[2], o[m]);
            o[m] = fmaf(hq[3], wv[3], o[m]);
        }
    }
    #pragma unroll
    for (int q = 0; q < 4; ++q) {
        f32x4 v; v[0]=o[4*q]; v[1]=o[4*q+1]; v[2]=o[4*q+2]; v[3]=o[4*q+3];
        *(f32x4*)&aclout[row * 16 + 4*q] = v;
    }
}

// ---------------------------------------------------------------------------
// Kernel 2: encoder  (B, 64) -> relu(64) -> (B, 32), per-thread row
// ---------------------------------------------------------------------------
__global__ __launch_bounds__(256, 2) void enc_kernel(
    const float* __restrict__ ob, const float* __restrict__ encW0,
    const float* __restrict__ encb0, const float* __restrict__ encW1,
    const float* __restrict__ encb1, float* __restrict__ y0ws)
{
    __shared__ float sW0[64 * 64];   // [j][k]
    __shared__ float sW1T[64 * 32];  // [j][n]
    __shared__ float sB0[64], sB1[32];
    const int tid = threadIdx.x;
    for (int i = tid; i < 64 * 64; i += 256) sW0[i] = encW0[i];
    for (int i = tid; i < 32 * 64; i += 256) { int n = i >> 6, j = i & 63; sW1T[j * 32 + n] = encW1[i]; }
    if (tid < 64) sB0[tid] = encb0[tid];
    if (tid < 32) sB1[tid] = encb1[tid];
    __syncthreads();

    const int row = blockIdx.x * 256 + tid;   // B rows
    f32x4 xv[16];
    #pragma unroll
    for (int q = 0; q < 16; ++q) xv[q] = *(const f32x4*)&ob[row * 64 + 4 * q];
    float o[32];
    #pragma unroll
    for (int n = 0; n < 32; ++n) o[n] = sB1[n];
    #pragma unroll 4
    for (int j = 0; j < 64; ++j) {
        float h = sB0[j];
        #pragma unroll
        for (int q = 0; q < 16; ++q) {
            const f32x4 wv = *(const f32x4*)&sW0[j * 64 + 4 * q];
            h = fmaf(xv[q][0], wv[0], h); h = fmaf(xv[q][1], wv[1], h);
            h = fmaf(xv[q][2], wv[2], h); h = fmaf(xv[q][3], wv[3], h);
        }
        h = fmaxf(h, 0.f);
        #pragma unroll
        for (int q = 0; q < 8; ++q) {
            const f32x4 wv = *(const f32x4*)&sW1T[j * 32 + 4 * q];
            o[4*q+0] = fmaf(h, wv[0], o[4*q+0]);
            o[4*q+1] = fmaf(h, wv[1], o[4*q+1]);
            o[4*q+2] = fmaf(h, wv[2], o[4*q+2]);
            o[4*q+3] = fmaf(h, wv[3], o[4*q+3]);
        }
    }
    #pragma unroll
    for (int q = 0; q < 8; ++q) {
        f32x4 v; v[0]=o[4*q]; v[1]=o[4*q+1]; v[2]=o[4*q+2]; v[3]=o[4*q+3];
        *(f32x4*)&y0ws[row * 32 + 4 * q] = v;
    }
}

// ---------------------------------------------------------------------------
// Kernel 3: ODE time loop + fused decoder. One wave = 16 batch elements.
// K=16 MFMA: the C/D row mapping (row = 4*quad + reg) equals the A/B k-mapping
// (k = 4*quad + j), so a C-layout state tile IS a valid B-operand after an
// f32->f16 pack — no transpose, no LDS, no barriers in the hot loop.
// Weights = stationary A-frags, 2-term f16 split (hi + 2048*residual) with
// separate accumulators recombined via fma(clo, 1/2048, chi): weights exact
// to ~2^-22. Stage inputs single-f16 (2^-11, quasi-random per stage).
// Decoder fused per save point (single-f16), C-tiles -> aligned f32x4 stores.
// ---------------------------------------------------------------------------
__global__ __launch_bounds__(64, 1) void ode_kernel(
    const float* __restrict__ dynW0, const float* __restrict__ dynb0,
    const float* __restrict__ dynW1, const float* __restrict__ dynb1,
    const float* __restrict__ decW0, const float* __restrict__ decb0,
    const float* __restrict__ decW1, const float* __restrict__ decb1,
    const float* __restrict__ times, const float* __restrict__ aclws,
    const float* __restrict__ y0ws,  float* __restrict__ out)
{
    __shared__ float tb[NT];

    const int lane  = threadIdx.x;   // 64
    const int g     = lane >> 4;     // quad
    const int col   = lane & 15;     // batch col within tile
    const int bbase = blockIdx.x * 16;
    const int bcol  = bbase + col;

    tb[lane]      = times[(size_t)bbase * NT + lane];
    tb[64 + lane] = times[(size_t)bbase * NT + 64 + lane];
    __builtin_amdgcn_wave_barrier();

    // ---- stationary weight A-frags: lane (g,col) holds W[16*mt+col][16*c+4g+j]
    f16x4 w0yH[4][2], w0yL[4][2], w0aH[4], w0aL[4], w1H[2][4], w1L[2][4];
    f16x4 dW0[4][2], dW1[4][4];
    #pragma unroll
    for (int mt = 0; mt < 4; ++mt) {
        #pragma unroll
        for (int c = 0; c < 2; ++c)
            split4(*(const f32x4*)&dynW0[(16 * mt + col) * 48 + 16 * c + 4 * g],
                   w0yH[mt][c], w0yL[mt][c]);
        split4(*(const f32x4*)&dynW0[(16 * mt + col) * 48 + 32 + 4 * g],
               w0aH[mt], w0aL[mt]);
        #pragma unroll
        for (int c = 0; c < 2; ++c)
            dW0[mt][c] = packC(*(const f32x4*)&decW0[(16 * mt + col) * 32 + 16 * c + 4 * g]);
        #pragma unroll
        for (int c = 0; c < 4; ++c)
            dW1[mt][c] = packC(*(const f32x4*)&decW1[(16 * mt + col) * 64 + 16 * c + 4 * g]);
    }
    #pragma unroll
    for (int ot = 0; ot < 2; ++ot)
        #pragma unroll
        for (int c = 0; c < 4; ++c)
            split4(*(const f32x4*)&dynW1[(16 * ot + col) * 64 + 16 * c + 4 * g],
                   w1H[ot][c], w1L[ot][c]);

    // ---- biases in C layout (broadcast over batch cols; depend on g only)
    f32x4 b0C[4], b1C[2], db0C[4], db1C[4];
    #pragma unroll
    for (int mt = 0; mt < 4; ++mt) {
        b0C[mt]  = *(const f32x4*)&dynb0[16 * mt + 4 * g];
        db0C[mt] = *(const f32x4*)&decb0[16 * mt + 4 * g];
        db1C[mt] = *(const f32x4*)&decb1[16 * mt + 4 * g];
    }
    #pragma unroll
    for (int ot = 0; ot < 2; ++ot)
        b1C[ot] = *(const f32x4*)&dynb1[16 * ot + 4 * g];

    // ---- y0 in C layout (Yᵀ: rows = feature 16t+4g+r, cols = batch)
    f32x4 y[2];
    y[0] = *(const f32x4*)&y0ws[(size_t)bcol * 32 + 4 * g];
    y[1] = *(const f32x4*)&y0ws[(size_t)bcol * 32 + 16 + 4 * g];

    // f: xs (2 C-tiles) + cin (4 C-tiles = b0 + W0a·acl) -> o (2 C-tiles)
    auto feval = [&](const f32x4* xs, const f32x4* cin, f32x4* o) {
        const f16x4 xb0 = packC(xs[0]);
        const f16x4 xb1 = packC(xs[1]);
        f16x4 hb[4];
        #pragma unroll
        for (int mt = 0; mt < 4; ++mt) {
            f32x4 chi = cin[mt];
            chi = MFMA16(w0yH[mt][0], xb0, chi);
            chi = MFMA16(w0yH[mt][1], xb1, chi);
            f32x4 clo = {0.f, 0.f, 0.f, 0.f};
            clo = MFMA16(w0yL[mt][0], xb0, clo);
            clo = MFMA16(w0yL[mt][1], xb1, clo);
            f32x4 hv;
            #pragma unroll
            for (int r = 0; r < 4; ++r) hv[r] = fmaxf(fmaf(clo[r], INV2048, chi[r]), 0.f);
            hb[mt] = packC(hv);
        }
        #pragma unroll
        for (int ot = 0; ot < 2; ++ot) {
            f32x4 chi = b1C[ot];
            f32x4 clo = {0.f, 0.f, 0.f, 0.f};
            #pragma unroll
            for (int c = 0; c < 4; ++c) {
                chi = MFMA16(w1H[ot][c], hb[c], chi);
                clo = MFMA16(w1L[ot][c], hb[c], clo);
            }
            #pragma unroll
            for (int r = 0; r < 4; ++r) o[ot][r] = fmaf(clo[r], INV2048, chi[r]);
        }
    };

    // fused decoder (single-f16): y C-tiles -> out[bcol][t][64]
    auto dec_store = [&](const f32x4* yv, int t) {
        const f16x4 yb0 = packC(yv[0]);
        const f16x4 yb1 = packC(yv[1]);
        f16x4 hb[4];
        #pragma unroll
        for (int mt = 0; mt < 4; ++mt) {
            f32x4 c = db0C[mt];
            c = MFMA16(dW0[mt][0], yb0, c);
            c = MFMA16(dW0[mt][1], yb1, c);
            hb[mt] = packC(relu4(c));
        }
        #pragma unroll
        for (int ot = 0; ot < 4; ++ot) {
            f32x4 c = db1C[ot];
            #pragma unroll
            for (int cc = 0; cc < 4; ++cc) c = MFMA16(dW1[ot][cc], hb[cc], c);
            *(f32x4*)&out[((size_t)bcol * NT + t) * 64 + 16 * ot + 4 * g] = c;
        }
    };

    // cacl = b0 + W0a·aclᵀ in C layout (acl = 16 feats = exactly one K-chunk);
    // acl itself split (hi + residual) for accuracy.
    auto acl_c = [&](const f32x4 av, f32x4* cd) {
        const f16x4 aH = packC(av);
        const f16x4 aL = pack4(av[0] - (float)aH[0], av[1] - (float)aH[1],
                               av[2] - (float)aH[2], av[3] - (float)aH[3]);
        #pragma unroll
        for (int mt = 0; mt < 4; ++mt) {
            f32x4 chi = b0C[mt];
            chi = MFMA16(w0aH[mt], aH, chi);
            chi = MFMA16(w0aH[mt], aL, chi);
            f32x4 clo = {0.f, 0.f, 0.f, 0.f};
            clo = MFMA16(w0aL[mt], aH, clo);
            #pragma unroll
            for (int r = 0; r < 4; ++r) cd[mt][r] = fmaf(clo[r], INV2048, chi[r]);
        }
    };
    auto load_acl = [&](int t) -> f32x4 {
        return *(const f32x4*)&aclws[((size_t)bcol * NT + t) * 16 + 4 * g];
    };

    dec_store(y, 0);

    // prime acl pipeline
    f32x4 caclC[4], caclN[4];
    acl_c(load_acl(0), caclC);
    f32x4 av = load_acl(1);

    for (int i = 0; i < NT - 1; ++i) {
        const float t0v = tb[i];
        const float t1v = tb[i + 1];
        const float hh  = (t1v - t0v) * 0.5f;     // /K, K=2

        acl_c(av, caclN);                          // interval i+1
        const int nxt = (i + 2 <= NT - 1) ? (i + 2) : (NT - 1);
        av = load_acl(nxt);

        #pragma unroll 1
        for (int sub = 0; sub < 2; ++sub) {
            const float tsub  = t0v + (float)sub * hh;
            // stage-6 time fl(tsub+hh): matches reference searchsorted('right')
            const bool  swap6 = (tsub + hh >= t1v);
            f32x4 c6[4];
            #pragma unroll
            for (int t = 0; t < 4; ++t) c6[t] = swap6 ? caclN[t] : caclC[t];

            f32x4 xs[2], k1[2], k2[2], k3[2], k4[2], k5[2], k6[2];
            feval(y, caclC, k1);
            #pragma unroll
            for (int t = 0; t < 2; ++t) xs[t] = y[t] + hh * (0.2f * k1[t]);
            feval(xs, caclC, k2);
            #pragma unroll
            for (int t = 0; t < 2; ++t) xs[t] = y[t] + hh * (0.075f * k1[t] + 0.225f * k2[t]);
            feval(xs, caclC, k3);
            #pragma unroll
            for (int t = 0; t < 2; ++t) xs[t] = y[t] + hh * ((float)(44.0/45.0) * k1[t]
                + (float)(-56.0/15.0) * k2[t] + (float)(32.0/9.0) * k3[t]);
            feval(xs, caclC, k4);
            #pragma unroll
            for (int t = 0; t < 2; ++t) xs[t] = y[t] + hh * ((float)(19372.0/6561.0) * k1[t]
                + (float)(-25360.0/2187.0) * k2[t] + (float)(64448.0/6561.0) * k3[t]
                + (float)(-212.0/729.0) * k4[t]);
            feval(xs, caclC, k5);
            #pragma unroll
            for (int t = 0; t < 2; ++t) xs[t] = y[t] + hh * ((float)(9017.0/3168.0) * k1[t]
                + (float)(-355.0/33.0) * k2[t] + (float)(46732.0/5247.0) * k3[t]
                + (float)(49.0/176.0) * k4[t] + (float)(-5103.0/18656.0) * k5[t]);
            feval(xs, c6, k6);
            #pragma unroll
            for (int t = 0; t < 2; ++t) y[t] = y[t] + hh * ((float)(35.0/384.0) * k1[t]
                + (float)(500.0/1113.0) * k3[t] + (float)(125.0/192.0) * k4[t]
                + (float)(-2187.0/6784.0) * k5[t] + (float)(11.0/84.0) * k6[t]);
        }
        #pragma unroll
        for (int t = 0; t < 4; ++t) caclC[t] = caclN[t];
        dec_store(y, i + 1);
    }
}

extern "C" void kernel_launch(void* const* d_in, const int* in_sizes, int n_in,
                              void* d_out, int out_size, void* d_ws, size_t ws_size,
                              hipStream_t stream)
{
    const float* encW0 = (const float*)d_in[0];
    const float* encb0 = (const float*)d_in[1];
    const float* encW1 = (const float*)d_in[2];
    const float* encb1 = (const float*)d_in[3];
    const float* acW0  = (const float*)d_in[4];
    const float* acb0  = (const float*)d_in[5];
    const float* acW1  = (const float*)d_in[6];
    const float* acb1  = (const float*)d_in[7];
    const float* dynW0 = (const float*)d_in[8];
    const float* dynb0 = (const float*)d_in[9];
    const float* dynW1 = (const float*)d_in[10];
    const float* dynb1 = (const float*)d_in[11];
    const float* decW0 = (const float*)d_in[12];
    const float* decb0 = (const float*)d_in[13];
    const float* decW1 = (const float*)d_in[14];
    const float* decb1 = (const float*)d_in[15];
    const float* ob    = (const float*)d_in[16];
    const float* acs   = (const float*)d_in[17];
    const float* times = (const float*)d_in[18];
    float* out = (float*)d_out;

    float* acl  = (float*)d_ws;                       // NB*NT*16 f32 = 16.78 MB
    float* ency = acl + (size_t)NB * NT * 16;         // NB*32      =  0.26 MB

    acl_kernel<<<(NB * NT) / 256, 256, 0, stream>>>(acs, acW0, acb0, acW1, acb1, acl);
    enc_kernel<<<NB / 256, 256, 0, stream>>>(ob, encW0, encb0, encW1, encb1, ency);
    ode_kernel<<<NB / 16, 64, 0, stream>>>(dynW0, dynb0, dynW1, dynb1,
                                           decW0, decb0, decW1, decb1,
                                           times, acl, ency, out);
}